// Round 1
// baseline (3076.693 us; speedup 1.0000x reference)
//
#include <hip/hip_runtime.h>
#include <math.h>

#define BB 8
#define NN 8192
#define SS 2048
#define KK 32
#define NP (BB*SS*KK)   /* 524288 points through the MLP */
#define EPSF 1e-5f

// ---------------------------------------------------------------------------
// FPS: one block per batch. Sequential 2048 iterations; dist + argmax kept
// bit-exact vs numpy ((dx*dx + dy*dy) + dz*dz, no FMA contraction, first-max
// tie break = smallest index). Writes new_xyz (exact coordinate copies).
// ---------------------------------------------------------------------------
__global__ __launch_bounds__(512) void fps_kernel(const float* __restrict__ xyz,
                                                  float* __restrict__ out_newxyz) {
    const int T = 512;
    const int PPT = NN / T;          // 16 points per thread
    int b = blockIdx.x;
    int t = threadIdx.x;
    const float* x = xyz + b * NN * 3;
    float* nout = out_newxyz + b * SS * 3;

    float px[PPT], py[PPT], pz[PPT], dist[PPT];
#pragma unroll
    for (int i = 0; i < PPT; i++) {
        int p = t + i * T;
        px[i] = x[p * 3 + 0];
        py[i] = x[p * 3 + 1];
        pz[i] = x[p * 3 + 2];
        dist[i] = 1e10f;
    }

    __shared__ float c_x, c_y, c_z;
    __shared__ unsigned s_gmax;
    __shared__ int s_gidx;

    if (t == 0) { c_x = px[0]; c_y = py[0]; c_z = pz[0]; }  // far = 0 initially
    __syncthreads();

    for (int it = 0; it < SS; it++) {
        float cx = c_x, cy = c_y, cz = c_z;
        if (t == 0) {
            nout[it * 3 + 0] = cx;
            nout[it * 3 + 1] = cy;
            nout[it * 3 + 2] = cz;
            s_gmax = 0u;
            s_gidx = NN;
        }
        // update min-dists; track local max (all dists >= 0)
        float lmax = -1.0f;
#pragma unroll
        for (int i = 0; i < PPT; i++) {
            float dx = __fsub_rn(px[i], cx);
            float dy = __fsub_rn(py[i], cy);
            float dz = __fsub_rn(pz[i], cz);
            float d  = __fadd_rn(__fadd_rn(__fmul_rn(dx, dx), __fmul_rn(dy, dy)),
                                 __fmul_rn(dz, dz));
            float dd = fminf(dist[i], d);
            dist[i] = dd;
            lmax = fmaxf(lmax, dd);
        }
        // wave butterfly max (all lanes end with wave max)
        float wmax = lmax;
#pragma unroll
        for (int off = 1; off < 64; off <<= 1)
            wmax = fmaxf(wmax, __shfl_xor(wmax, off));
        __syncthreads();                                  // resets visible
        if ((t & 63) == 0) atomicMax(&s_gmax, __float_as_uint(wmax)); // uint order == float order for >=0
        __syncthreads();
        float gmax = __uint_as_float(s_gmax);
        if (wmax == gmax) {                               // only winning wave(s) rescan
            int cand = NN;
#pragma unroll
            for (int i = PPT - 1; i >= 0; i--)
                if (dist[i] == gmax) cand = t + i * T;    // downward: smallest idx wins
            if (cand < NN) atomicMin(&s_gidx, cand);
        }
        __syncthreads();
        int gi = s_gidx;
        if (t == (gi & (T - 1))) {                        // owner writes next centroid from regs (bit-exact)
            int ii = gi >> 9;
            float vx = px[0], vy = py[0], vz = pz[0];
#pragma unroll
            for (int j = 1; j < PPT; j++)
                if (ii == j) { vx = px[j]; vy = py[j]; vz = pz[j]; }
            c_x = vx; c_y = vy; c_z = vz;
        }
        __syncthreads();
    }
}

// ---------------------------------------------------------------------------
// Ball query: one wave per query. Ordered compaction of first 32 in-radius
// indices (== reference's where->sort->truncate), pad with first index.
// ---------------------------------------------------------------------------
__global__ __launch_bounds__(256) void ballq_kernel(const float* __restrict__ xyz,
                                                    const float* __restrict__ new_xyz,
                                                    int* __restrict__ idx_out) {
    int q    = blockIdx.x * 4 + (threadIdx.x >> 6);
    int lane = threadIdx.x & 63;
    int b    = q >> 11;                        // q / SS
    const float* x = xyz + b * NN * 3;
    const float* c = new_xyz + q * 3;
    float cx = c[0], cy = c[1], cz = c[2];
    int* out = idx_out + q * KK;
    const float R2 = (float)(0.2 * 0.2);       // match reference double->f32 cast

    int count = 0;
    int first = -1;
    for (int base = 0; base < NN; base += 64) {
        int p = base + lane;
        float dx = __fsub_rn(x[p * 3 + 0], cx);
        float dy = __fsub_rn(x[p * 3 + 1], cy);
        float dz = __fsub_rn(x[p * 3 + 2], cz);
        float d  = __fadd_rn(__fadd_rn(__fmul_rn(dx, dx), __fmul_rn(dy, dy)),
                             __fmul_rn(dz, dz));
        bool in = !(d > R2);
        unsigned long long m = __ballot(in);
        if (first < 0 && m != 0ull) first = base + __ffsll((unsigned long long)m) - 1;
        int pre = __popcll(m & ((1ull << lane) - 1ull));
        int pos = count + pre;
        if (in && pos < KK) out[pos] = p;
        count += __popcll(m);
        if (count >= KK) break;                 // wave-uniform
    }
    for (int i2 = count + lane; i2 < KK; i2 += 64) out[i2] = first;
}

// ---------------------------------------------------------------------------
// MLP helpers (thread-per-point recompute chain; weights via uniform s_loads)
// ---------------------------------------------------------------------------
__device__ __forceinline__ void load_in6(const float* __restrict__ xyz,
                                         const float* __restrict__ points,
                                         const float* __restrict__ new_xyz,
                                         const int* __restrict__ idx, int p, float inx[6]) {
    int bs = p >> 5;
    int b  = bs >> 11;
    int pt = idx[p];
    const float* xb = xyz + ((long)b * NN + pt) * 3;
    const float* pb = points + ((long)b * NN + pt) * 3;
    const float* nx = new_xyz + bs * 3;
    inx[0] = xb[0] - nx[0];
    inx[1] = xb[1] - nx[1];
    inx[2] = xb[2] - nx[2];
    inx[3] = pb[0];
    inx[4] = pb[1];
    inx[5] = pb[2];
}

template <int CIN, int COUT>
__device__ __forceinline__ void linear(const float* __restrict__ w,
                                       const float* __restrict__ bias,
                                       const float* xin, float* yout) {
#pragma unroll
    for (int o = 0; o < COUT; o++) {
        float acc = bias[o];
#pragma unroll
        for (int j = 0; j < CIN; j++) acc = fmaf(w[o * CIN + j], xin[j], acc);
        yout[o] = acc;
    }
}

// compute per-channel BN scale/shift from raw sums (threads 0..C-1)
template <int C>
__device__ __forceinline__ void bn_coef(const float* __restrict__ stats,
                                        const float* __restrict__ g,
                                        const float* __restrict__ be,
                                        float* s_sc, float* s_sh) {
    int t = threadIdx.x;
    if (t < C) {
        float mean = stats[t] * (1.0f / (float)NP);
        float var  = stats[C + t] * (1.0f / (float)NP) - mean * mean;
        float rstd = 1.0f / sqrtf(var + EPSF);
        float sc = g[t] * rstd;
        s_sc[t] = sc;
        s_sh[t] = be[t] - mean * sc;
    }
    __syncthreads();
}

// block-level channel sums via LDS transpose (33.8KB), one atomic/chan/block
template <int C>
__device__ __forceinline__ void accum_stats(const float* y, float* __restrict__ gstats) {
    __shared__ float buf[256][33];
    int t = threadIdx.x;
#pragma unroll
    for (int h = 0; h < C / 32; h++) {
        __syncthreads();
#pragma unroll
        for (int c = 0; c < 32; c++) buf[t][c] = y[h * 32 + c];
        __syncthreads();
        if (t < 32) {
            float s = 0.f, sq = 0.f;
            for (int r = 0; r < 256; r++) {
                float v = buf[r][t];
                s += v;
                sq = fmaf(v, v, sq);
            }
            atomicAdd(&gstats[h * 32 + t], s);
            atomicAdd(&gstats[C + h * 32 + t], sq);
        }
    }
}

__global__ __launch_bounds__(256) void l0_stats_kernel(
    const float* __restrict__ xyz, const float* __restrict__ points,
    const float* __restrict__ new_xyz, const int* __restrict__ idx,
    const float* __restrict__ w0, const float* __restrict__ b0_,
    float* __restrict__ stats0) {
    int p = blockIdx.x * 256 + threadIdx.x;
    float inx[6];
    load_in6(xyz, points, new_xyz, idx, p, inx);
    float y0[32];
    linear<6, 32>(w0, b0_, inx, y0);
    accum_stats<32>(y0, stats0);
}

__global__ __launch_bounds__(256) void l1_stats_kernel(
    const float* __restrict__ xyz, const float* __restrict__ points,
    const float* __restrict__ new_xyz, const int* __restrict__ idx,
    const float* __restrict__ w0, const float* __restrict__ b0_,
    const float* __restrict__ g0, const float* __restrict__ be0,
    const float* __restrict__ w1, const float* __restrict__ b1_,
    const float* __restrict__ stats0, float* __restrict__ stats1) {
    __shared__ float sc0[32], sh0[32];
    bn_coef<32>(stats0, g0, be0, sc0, sh0);
    int p = blockIdx.x * 256 + threadIdx.x;
    float inx[6];
    load_in6(xyz, points, new_xyz, idx, p, inx);
    float y0[32];
    linear<6, 32>(w0, b0_, inx, y0);
#pragma unroll
    for (int c = 0; c < 32; c++) y0[c] = fmaxf(fmaf(y0[c], sc0[c], sh0[c]), 0.f);
    float y1[32];
    linear<32, 32>(w1, b1_, y0, y1);
    accum_stats<32>(y1, stats1);
}

__global__ __launch_bounds__(256) void l2_stats_kernel(
    const float* __restrict__ xyz, const float* __restrict__ points,
    const float* __restrict__ new_xyz, const int* __restrict__ idx,
    const float* __restrict__ w0, const float* __restrict__ b0_,
    const float* __restrict__ g0, const float* __restrict__ be0,
    const float* __restrict__ w1, const float* __restrict__ b1_,
    const float* __restrict__ g1, const float* __restrict__ be1,
    const float* __restrict__ w2, const float* __restrict__ b2_,
    const float* __restrict__ stats0, const float* __restrict__ stats1,
    float* __restrict__ stats2) {
    __shared__ float sc0[32], sh0[32], sc1[32], sh1[32];
    bn_coef<32>(stats0, g0, be0, sc0, sh0);
    bn_coef<32>(stats1, g1, be1, sc1, sh1);
    int p = blockIdx.x * 256 + threadIdx.x;
    float inx[6];
    load_in6(xyz, points, new_xyz, idx, p, inx);
    float y0[32];
    linear<6, 32>(w0, b0_, inx, y0);
#pragma unroll
    for (int c = 0; c < 32; c++) y0[c] = fmaxf(fmaf(y0[c], sc0[c], sh0[c]), 0.f);
    float y1[32];
    linear<32, 32>(w1, b1_, y0, y1);
#pragma unroll
    for (int c = 0; c < 32; c++) y1[c] = fmaxf(fmaf(y1[c], sc1[c], sh1[c]), 0.f);
    float y2[64];
    linear<32, 64>(w2, b2_, y1, y2);
    accum_stats<64>(y2, stats2);
}

__global__ __launch_bounds__(256) void final_kernel(
    const float* __restrict__ xyz, const float* __restrict__ points,
    const float* __restrict__ new_xyz, const int* __restrict__ idx,
    const float* __restrict__ w0, const float* __restrict__ b0_,
    const float* __restrict__ g0, const float* __restrict__ be0,
    const float* __restrict__ w1, const float* __restrict__ b1_,
    const float* __restrict__ g1, const float* __restrict__ be1,
    const float* __restrict__ w2, const float* __restrict__ b2_,
    const float* __restrict__ g2, const float* __restrict__ be2,
    const float* __restrict__ stats0, const float* __restrict__ stats1,
    const float* __restrict__ stats2, float* __restrict__ out_points) {
    __shared__ float sc0[32], sh0[32], sc1[32], sh1[32], sc2[64], sh2[64];
    bn_coef<32>(stats0, g0, be0, sc0, sh0);
    bn_coef<32>(stats1, g1, be1, sc1, sh1);
    bn_coef<64>(stats2, g2, be2, sc2, sh2);
    int p = blockIdx.x * 256 + threadIdx.x;
    float inx[6];
    load_in6(xyz, points, new_xyz, idx, p, inx);
    float y0[32];
    linear<6, 32>(w0, b0_, inx, y0);
#pragma unroll
    for (int c = 0; c < 32; c++) y0[c] = fmaxf(fmaf(y0[c], sc0[c], sh0[c]), 0.f);
    float y1[32];
    linear<32, 32>(w1, b1_, y0, y1);
#pragma unroll
    for (int c = 0; c < 32; c++) y1[c] = fmaxf(fmaf(y1[c], sc1[c], sh1[c]), 0.f);
    float y2[64];
    linear<32, 64>(w2, b2_, y1, y2);
    // BN + relu + max over k (k == lane&31; butterfly within each 32-lane half)
#pragma unroll
    for (int c = 0; c < 64; c++) {
        float v = fmaxf(fmaf(y2[c], sc2[c], sh2[c]), 0.f);
#pragma unroll
        for (int off = 1; off < 32; off <<= 1)
            v = fmaxf(v, __shfl_xor(v, off));
        y2[c] = v;
    }
    int lane = threadIdx.x & 63;
    if ((lane & 31) == 0) {                     // k == 0 lanes write their (b,s) row
        int bs = p >> 5;
        float4* o = (float4*)(out_points + (long)bs * 64);
#pragma unroll
        for (int c4 = 0; c4 < 16; c4++)
            o[c4] = make_float4(y2[c4 * 4], y2[c4 * 4 + 1], y2[c4 * 4 + 2], y2[c4 * 4 + 3]);
    }
}

// ---------------------------------------------------------------------------
extern "C" void kernel_launch(void* const* d_in, const int* in_sizes, int n_in,
                              void* d_out, int out_size, void* d_ws, size_t ws_size,
                              hipStream_t stream) {
    (void)in_sizes; (void)n_in; (void)out_size; (void)ws_size;
    const float* xyz    = (const float*)d_in[0];
    const float* points = (const float*)d_in[1];
    const float* w0  = (const float*)d_in[2];
    const float* b0_ = (const float*)d_in[3];
    const float* g0  = (const float*)d_in[4];
    const float* be0 = (const float*)d_in[5];
    const float* w1  = (const float*)d_in[6];
    const float* b1_ = (const float*)d_in[7];
    const float* g1  = (const float*)d_in[8];
    const float* be1 = (const float*)d_in[9];
    const float* w2  = (const float*)d_in[10];
    const float* b2_ = (const float*)d_in[11];
    const float* g2  = (const float*)d_in[12];
    const float* be2 = (const float*)d_in[13];

    float* out        = (float*)d_out;
    float* out_newxyz = out;                 // (8,2048,3)
    float* out_points = out + BB * SS * 3;   // (8,2048,64)

    int*   idx    = (int*)d_ws;              // NP ints = 2MB
    float* stats  = (float*)d_ws + NP;
    float* stats0 = stats;                   // 64 floats (sum32+sq32)
    float* stats1 = stats + 64;              // 64 floats
    float* stats2 = stats + 128;             // 128 floats (sum64+sq64)

    hipMemsetAsync(stats, 0, 256 * sizeof(float), stream);

    fps_kernel<<<BB, 512, 0, stream>>>(xyz, out_newxyz);
    ballq_kernel<<<BB * SS / 4, 256, 0, stream>>>(xyz, out_newxyz, idx);
    l0_stats_kernel<<<NP / 256, 256, 0, stream>>>(xyz, points, out_newxyz, idx, w0, b0_, stats0);
    l1_stats_kernel<<<NP / 256, 256, 0, stream>>>(xyz, points, out_newxyz, idx,
                                                  w0, b0_, g0, be0, w1, b1_, stats0, stats1);
    l2_stats_kernel<<<NP / 256, 256, 0, stream>>>(xyz, points, out_newxyz, idx,
                                                  w0, b0_, g0, be0, w1, b1_, g1, be1,
                                                  w2, b2_, stats0, stats1, stats2);
    final_kernel<<<NP / 256, 256, 0, stream>>>(xyz, points, out_newxyz, idx,
                                               w0, b0_, g0, be0, w1, b1_, g1, be1,
                                               w2, b2_, g2, be2, stats0, stats1, stats2,
                                               out_points);
}

// Round 2
// 2621.216 us; speedup vs baseline: 1.1738x; 1.1738x over previous
//
#include <hip/hip_runtime.h>
#include <math.h>

#define BB 8
#define NN 8192
#define SS 2048
#define KK 32
#define NP (BB*SS*KK)   /* 524288 points through the MLP */
#define EPSF 1e-5f

// ---------------------------------------------------------------------------
// FPS: one block per batch, 512 threads, ONE barrier per iteration.
// - per-thread (lmax, slot) tracking during dist update (strict >, first wins
//   => smallest index among ties, matching np.argmax)
// - u64 key = (dist_bits<<32) | ~p  -> wave butterfly max = argmax w/ correct
//   tie-break; wave leaders write parity-double-buffered LDS slots (no reset,
//   no atomics); all threads max 8 slots and read the next centroid from a
//   full LDS copy of xyz (broadcast read, no owner-broadcast phase).
// Bit-exact: __f*_rn dist chain ((dx*dx+dy*dy)+dz*dz), exact coord copies.
// ---------------------------------------------------------------------------
__global__ __launch_bounds__(512) void fps_kernel(const float* __restrict__ xyz,
                                                  float* __restrict__ out_newxyz) {
    const int T = 512;
    const int PPT = NN / T;          // 16 points per thread
    int b = blockIdx.x;
    int t = threadIdx.x;
    int wid  = t >> 6;
    int lane = t & 63;
    const float* x = xyz + b * NN * 3;
    float* nout = out_newxyz + b * SS * 3;

    __shared__ float lx[NN], ly[NN], lz[NN];          // 96 KB coord copy
    __shared__ unsigned long long skey[2][8];         // parity-buffered wave keys

    float px[PPT], py[PPT], pz[PPT], dist[PPT];
#pragma unroll
    for (int i = 0; i < PPT; i++) {
        int p = t + i * T;
        float vx = x[p * 3 + 0];
        float vy = x[p * 3 + 1];
        float vz = x[p * 3 + 2];
        px[i] = vx; py[i] = vy; pz[i] = vz;
        lx[p] = vx; ly[p] = vy; lz[p] = vz;
        dist[i] = 1e10f;
    }
    __syncthreads();
    float cx = lx[0], cy = ly[0], cz = lz[0];         // far = 0 initially

    for (int it = 0; it < SS; it++) {
        if (t == 0) {                                  // record current far point
            nout[it * 3 + 0] = cx;
            nout[it * 3 + 1] = cy;
            nout[it * 3 + 2] = cz;
        }
        // update min-dists; track (lmax, slot) in-register
        float lmax = -1.0f;
        int   li   = 0;
#pragma unroll
        for (int i = 0; i < PPT; i++) {
            float dx = __fsub_rn(px[i], cx);
            float dy = __fsub_rn(py[i], cy);
            float dz = __fsub_rn(pz[i], cz);
            float d  = __fadd_rn(__fadd_rn(__fmul_rn(dx, dx), __fmul_rn(dy, dy)),
                                 __fmul_rn(dz, dz));
            float dd = fminf(dist[i], d);
            dist[i] = dd;
            bool gt = dd > lmax;                       // strict: first (smallest i) wins
            lmax = gt ? dd : lmax;
            li   = gt ? i  : li;
        }
        int p = t + (li << 9);
        unsigned long long key =
            ((unsigned long long)__float_as_uint(lmax) << 32) | (unsigned)(~p);
        // wave butterfly max (u64): max dist, ties -> larger ~p = smaller p
#pragma unroll
        for (int off = 1; off < 64; off <<= 1) {
            unsigned long long o = __shfl_xor(key, off);
            key = (o > key) ? o : key;
        }
        if (lane == 0) skey[it & 1][wid] = key;
        __syncthreads();
        unsigned long long k = skey[it & 1][0];
#pragma unroll
        for (int j = 1; j < 8; j++) {
            unsigned long long o = skey[it & 1][j];
            k = (o > k) ? o : k;
        }
        int gi = (int)(~(unsigned)k) & (NN - 1);
        cx = lx[gi]; cy = ly[gi]; cz = lz[gi];         // broadcast LDS read
    }
}

// ---------------------------------------------------------------------------
// Ball query: one wave per query. Ordered compaction of first 32 in-radius
// indices (== reference's where->sort->truncate), pad with first index.
// ---------------------------------------------------------------------------
__global__ __launch_bounds__(256) void ballq_kernel(const float* __restrict__ xyz,
                                                    const float* __restrict__ new_xyz,
                                                    int* __restrict__ idx_out) {
    int q    = blockIdx.x * 4 + (threadIdx.x >> 6);
    int lane = threadIdx.x & 63;
    int b    = q >> 11;                        // q / SS
    const float* x = xyz + b * NN * 3;
    const float* c = new_xyz + q * 3;
    float cx = c[0], cy = c[1], cz = c[2];
    int* out = idx_out + q * KK;
    const float R2 = (float)(0.2 * 0.2);       // match reference double->f32 cast

    int count = 0;
    int first = -1;
    for (int base = 0; base < NN; base += 64) {
        int p = base + lane;
        float dx = __fsub_rn(x[p * 3 + 0], cx);
        float dy = __fsub_rn(x[p * 3 + 1], cy);
        float dz = __fsub_rn(x[p * 3 + 2], cz);
        float d  = __fadd_rn(__fadd_rn(__fmul_rn(dx, dx), __fmul_rn(dy, dy)),
                             __fmul_rn(dz, dz));
        bool in = !(d > R2);
        unsigned long long m = __ballot(in);
        if (first < 0 && m != 0ull) first = base + __ffsll((unsigned long long)m) - 1;
        int pre = __popcll(m & ((1ull << lane) - 1ull));
        int pos = count + pre;
        if (in && pos < KK) out[pos] = p;
        count += __popcll(m);
        if (count >= KK) break;                 // wave-uniform
    }
    for (int i2 = count + lane; i2 < KK; i2 += 64) out[i2] = first;
}

// ---------------------------------------------------------------------------
// MLP helpers (thread-per-point recompute chain; weights via uniform s_loads)
// ---------------------------------------------------------------------------
__device__ __forceinline__ void load_in6(const float* __restrict__ xyz,
                                         const float* __restrict__ points,
                                         const float* __restrict__ new_xyz,
                                         const int* __restrict__ idx, int p, float inx[6]) {
    int bs = p >> 5;
    int b  = bs >> 11;
    int pt = idx[p];
    const float* xb = xyz + ((long)b * NN + pt) * 3;
    const float* pb = points + ((long)b * NN + pt) * 3;
    const float* nx = new_xyz + bs * 3;
    inx[0] = xb[0] - nx[0];
    inx[1] = xb[1] - nx[1];
    inx[2] = xb[2] - nx[2];
    inx[3] = pb[0];
    inx[4] = pb[1];
    inx[5] = pb[2];
}

template <int CIN, int COUT>
__device__ __forceinline__ void linear(const float* __restrict__ w,
                                       const float* __restrict__ bias,
                                       const float* xin, float* yout) {
#pragma unroll
    for (int o = 0; o < COUT; o++) {
        float acc = bias[o];
#pragma unroll
        for (int j = 0; j < CIN; j++) acc = fmaf(w[o * CIN + j], xin[j], acc);
        yout[o] = acc;
    }
}

// compute per-channel BN scale/shift from raw sums (threads 0..C-1)
template <int C>
__device__ __forceinline__ void bn_coef(const float* __restrict__ stats,
                                        const float* __restrict__ g,
                                        const float* __restrict__ be,
                                        float* s_sc, float* s_sh) {
    int t = threadIdx.x;
    if (t < C) {
        float mean = stats[t] * (1.0f / (float)NP);
        float var  = stats[C + t] * (1.0f / (float)NP) - mean * mean;
        float rstd = 1.0f / sqrtf(var + EPSF);
        float sc = g[t] * rstd;
        s_sc[t] = sc;
        s_sh[t] = be[t] - mean * sc;
    }
    __syncthreads();
}

// block-level channel sums via LDS transpose (33.8KB), one atomic/chan/block
template <int C>
__device__ __forceinline__ void accum_stats(const float* y, float* __restrict__ gstats) {
    __shared__ float buf[256][33];
    int t = threadIdx.x;
#pragma unroll
    for (int h = 0; h < C / 32; h++) {
        __syncthreads();
#pragma unroll
        for (int c = 0; c < 32; c++) buf[t][c] = y[h * 32 + c];
        __syncthreads();
        if (t < 32) {
            float s = 0.f, sq = 0.f;
            for (int r = 0; r < 256; r++) {
                float v = buf[r][t];
                s += v;
                sq = fmaf(v, v, sq);
            }
            atomicAdd(&gstats[h * 32 + t], s);
            atomicAdd(&gstats[C + h * 32 + t], sq);
        }
    }
}

__global__ __launch_bounds__(256) void l0_stats_kernel(
    const float* __restrict__ xyz, const float* __restrict__ points,
    const float* __restrict__ new_xyz, const int* __restrict__ idx,
    const float* __restrict__ w0, const float* __restrict__ b0_,
    float* __restrict__ stats0) {
    int p = blockIdx.x * 256 + threadIdx.x;
    float inx[6];
    load_in6(xyz, points, new_xyz, idx, p, inx);
    float y0[32];
    linear<6, 32>(w0, b0_, inx, y0);
    accum_stats<32>(y0, stats0);
}

__global__ __launch_bounds__(256) void l1_stats_kernel(
    const float* __restrict__ xyz, const float* __restrict__ points,
    const float* __restrict__ new_xyz, const int* __restrict__ idx,
    const float* __restrict__ w0, const float* __restrict__ b0_,
    const float* __restrict__ g0, const float* __restrict__ be0,
    const float* __restrict__ w1, const float* __restrict__ b1_,
    const float* __restrict__ stats0, float* __restrict__ stats1) {
    __shared__ float sc0[32], sh0[32];
    bn_coef<32>(stats0, g0, be0, sc0, sh0);
    int p = blockIdx.x * 256 + threadIdx.x;
    float inx[6];
    load_in6(xyz, points, new_xyz, idx, p, inx);
    float y0[32];
    linear<6, 32>(w0, b0_, inx, y0);
#pragma unroll
    for (int c = 0; c < 32; c++) y0[c] = fmaxf(fmaf(y0[c], sc0[c], sh0[c]), 0.f);
    float y1[32];
    linear<32, 32>(w1, b1_, y0, y1);
    accum_stats<32>(y1, stats1);
}

__global__ __launch_bounds__(256) void l2_stats_kernel(
    const float* __restrict__ xyz, const float* __restrict__ points,
    const float* __restrict__ new_xyz, const int* __restrict__ idx,
    const float* __restrict__ w0, const float* __restrict__ b0_,
    const float* __restrict__ g0, const float* __restrict__ be0,
    const float* __restrict__ w1, const float* __restrict__ b1_,
    const float* __restrict__ g1, const float* __restrict__ be1,
    const float* __restrict__ w2, const float* __restrict__ b2_,
    const float* __restrict__ stats0, const float* __restrict__ stats1,
    float* __restrict__ stats2) {
    __shared__ float sc0[32], sh0[32], sc1[32], sh1[32];
    bn_coef<32>(stats0, g0, be0, sc0, sh0);
    bn_coef<32>(stats1, g1, be1, sc1, sh1);
    int p = blockIdx.x * 256 + threadIdx.x;
    float inx[6];
    load_in6(xyz, points, new_xyz, idx, p, inx);
    float y0[32];
    linear<6, 32>(w0, b0_, inx, y0);
#pragma unroll
    for (int c = 0; c < 32; c++) y0[c] = fmaxf(fmaf(y0[c], sc0[c], sh0[c]), 0.f);
    float y1[32];
    linear<32, 32>(w1, b1_, y0, y1);
#pragma unroll
    for (int c = 0; c < 32; c++) y1[c] = fmaxf(fmaf(y1[c], sc1[c], sh1[c]), 0.f);
    float y2[64];
    linear<32, 64>(w2, b2_, y1, y2);
    accum_stats<64>(y2, stats2);
}

__global__ __launch_bounds__(256) void final_kernel(
    const float* __restrict__ xyz, const float* __restrict__ points,
    const float* __restrict__ new_xyz, const int* __restrict__ idx,
    const float* __restrict__ w0, const float* __restrict__ b0_,
    const float* __restrict__ g0, const float* __restrict__ be0,
    const float* __restrict__ w1, const float* __restrict__ b1_,
    const float* __restrict__ g1, const float* __restrict__ be1,
    const float* __restrict__ w2, const float* __restrict__ b2_,
    const float* __restrict__ g2, const float* __restrict__ be2,
    const float* __restrict__ stats0, const float* __restrict__ stats1,
    const float* __restrict__ stats2, float* __restrict__ out_points) {
    __shared__ float sc0[32], sh0[32], sc1[32], sh1[32], sc2[64], sh2[64];
    bn_coef<32>(stats0, g0, be0, sc0, sh0);
    bn_coef<32>(stats1, g1, be1, sc1, sh1);
    bn_coef<64>(stats2, g2, be2, sc2, sh2);
    int p = blockIdx.x * 256 + threadIdx.x;
    float inx[6];
    load_in6(xyz, points, new_xyz, idx, p, inx);
    float y0[32];
    linear<6, 32>(w0, b0_, inx, y0);
#pragma unroll
    for (int c = 0; c < 32; c++) y0[c] = fmaxf(fmaf(y0[c], sc0[c], sh0[c]), 0.f);
    float y1[32];
    linear<32, 32>(w1, b1_, y0, y1);
#pragma unroll
    for (int c = 0; c < 32; c++) y1[c] = fmaxf(fmaf(y1[c], sc1[c], sh1[c]), 0.f);
    float y2[64];
    linear<32, 64>(w2, b2_, y1, y2);
    // BN + relu + max over k (k == lane&31; butterfly within each 32-lane half)
#pragma unroll
    for (int c = 0; c < 64; c++) {
        float v = fmaxf(fmaf(y2[c], sc2[c], sh2[c]), 0.f);
#pragma unroll
        for (int off = 1; off < 32; off <<= 1)
            v = fmaxf(v, __shfl_xor(v, off));
        y2[c] = v;
    }
    int lane = threadIdx.x & 63;
    if ((lane & 31) == 0) {                     // k == 0 lanes write their (b,s) row
        int bs = p >> 5;
        float4* o = (float4*)(out_points + (long)bs * 64);
#pragma unroll
        for (int c4 = 0; c4 < 16; c4++)
            o[c4] = make_float4(y2[c4 * 4], y2[c4 * 4 + 1], y2[c4 * 4 + 2], y2[c4 * 4 + 3]);
    }
}

// ---------------------------------------------------------------------------
extern "C" void kernel_launch(void* const* d_in, const int* in_sizes, int n_in,
                              void* d_out, int out_size, void* d_ws, size_t ws_size,
                              hipStream_t stream) {
    (void)in_sizes; (void)n_in; (void)out_size; (void)ws_size;
    const float* xyz    = (const float*)d_in[0];
    const float* points = (const float*)d_in[1];
    const float* w0  = (const float*)d_in[2];
    const float* b0_ = (const float*)d_in[3];
    const float* g0  = (const float*)d_in[4];
    const float* be0 = (const float*)d_in[5];
    const float* w1  = (const float*)d_in[6];
    const float* b1_ = (const float*)d_in[7];
    const float* g1  = (const float*)d_in[8];
    const float* be1 = (const float*)d_in[9];
    const float* w2  = (const float*)d_in[10];
    const float* b2_ = (const float*)d_in[11];
    const float* g2  = (const float*)d_in[12];
    const float* be2 = (const float*)d_in[13];

    float* out        = (float*)d_out;
    float* out_newxyz = out;                 // (8,2048,3)
    float* out_points = out + BB * SS * 3;   // (8,2048,64)

    int*   idx    = (int*)d_ws;              // NP ints = 2MB
    float* stats  = (float*)d_ws + NP;
    float* stats0 = stats;                   // 64 floats (sum32+sq32)
    float* stats1 = stats + 64;              // 64 floats
    float* stats2 = stats + 128;             // 128 floats (sum64+sq64)

    hipMemsetAsync(stats, 0, 256 * sizeof(float), stream);

    fps_kernel<<<BB, 512, 0, stream>>>(xyz, out_newxyz);
    ballq_kernel<<<BB * SS / 4, 256, 0, stream>>>(xyz, out_newxyz, idx);
    l0_stats_kernel<<<NP / 256, 256, 0, stream>>>(xyz, points, out_newxyz, idx, w0, b0_, stats0);
    l1_stats_kernel<<<NP / 256, 256, 0, stream>>>(xyz, points, out_newxyz, idx,
                                                  w0, b0_, g0, be0, w1, b1_, stats0, stats1);
    l2_stats_kernel<<<NP / 256, 256, 0, stream>>>(xyz, points, out_newxyz, idx,
                                                  w0, b0_, g0, be0, w1, b1_, g1, be1,
                                                  w2, b2_, stats0, stats1, stats2);
    final_kernel<<<NP / 256, 256, 0, stream>>>(xyz, points, out_newxyz, idx,
                                               w0, b0_, g0, be0, w1, b1_, g1, be1,
                                               w2, b2_, g2, be2, stats0, stats1, stats2,
                                               out_points);
}

// Round 3
// 2389.132 us; speedup vs baseline: 1.2878x; 1.0971x over previous
//
#include <hip/hip_runtime.h>
#include <math.h>

#define BB 8
#define NN 8192
#define SS 2048
#define KK 32
#define NP (BB*SS*KK)   /* 524288 points through the MLP */
#define EPSF 1e-5f

// ---------------------------------------------------------------------------
// DPP-based wave64 max of a u64 key (dist_bits<<32 | ~p). Pure VALU:
// row_shr 1/2/4/8 then row_bcast:15, row_bcast:31 -> lane 63 holds wave max.
// ---------------------------------------------------------------------------
template <int CTRL>
__device__ __forceinline__ unsigned long long dpp_max_step(unsigned long long key) {
    unsigned lo = (unsigned)key, hi = (unsigned)(key >> 32);
    unsigned nlo = (unsigned)__builtin_amdgcn_update_dpp((int)lo, (int)lo, CTRL, 0xf, 0xf, false);
    unsigned nhi = (unsigned)__builtin_amdgcn_update_dpp((int)hi, (int)hi, CTRL, 0xf, 0xf, false);
    unsigned long long nk = ((unsigned long long)nhi << 32) | nlo;
    return nk > key ? nk : key;
}

__device__ __forceinline__ unsigned long long wave_max_u64(unsigned long long key) {
    key = dpp_max_step<0x111>(key);  // row_shr:1
    key = dpp_max_step<0x112>(key);  // row_shr:2
    key = dpp_max_step<0x114>(key);  // row_shr:4
    key = dpp_max_step<0x118>(key);  // row_shr:8
    key = dpp_max_step<0x142>(key);  // row_bcast:15
    key = dpp_max_step<0x143>(key);  // row_bcast:31
    return key;                      // valid in lane 63
}

// ---------------------------------------------------------------------------
// FPS: one block per batch, 512 threads, ONE barrier per iteration.
// - per-thread (lmax, slot) tracking during dist update (strict >, first wins
//   => smallest index among ties, matching np.argmax)
// - u64 key = (dist_bits<<32) | ~p -> DPP wave max (VALU-only); lane 63 of
//   each wave writes parity-double-buffered LDS slot; all threads max the 8
//   slots and fetch the next centroid from a float4 LDS copy of xyz
//   (single broadcast ds_read_b128).
// Bit-exact: __f*_rn dist chain ((dx*dx+dy*dy)+dz*dz), exact coord copies.
// ---------------------------------------------------------------------------
__global__ __launch_bounds__(512) void fps_kernel(const float* __restrict__ xyz,
                                                  float* __restrict__ out_newxyz) {
    const int T = 512;
    const int PPT = NN / T;          // 16 points per thread
    int b = blockIdx.x;
    int t = threadIdx.x;
    int wid  = t >> 6;
    int lane = t & 63;
    const float* x = xyz + b * NN * 3;
    float* nout = out_newxyz + b * SS * 3;

    __shared__ float4 lxyz[NN];                       // 128 KB coord copy
    __shared__ unsigned long long skey[2][8];         // parity-buffered wave keys

    float px[PPT], py[PPT], pz[PPT], dist[PPT];
#pragma unroll
    for (int i = 0; i < PPT; i++) {
        int p = t + i * T;
        float vx = x[p * 3 + 0];
        float vy = x[p * 3 + 1];
        float vz = x[p * 3 + 2];
        px[i] = vx; py[i] = vy; pz[i] = vz;
        lxyz[p] = make_float4(vx, vy, vz, 0.f);
        dist[i] = 1e10f;
    }
    __syncthreads();
    float4 c0 = lxyz[0];                              // far = 0 initially
    float cx = c0.x, cy = c0.y, cz = c0.z;

    for (int it = 0; it < SS; it++) {
        if (t == 0) {                                  // record current far point
            nout[it * 3 + 0] = cx;
            nout[it * 3 + 1] = cy;
            nout[it * 3 + 2] = cz;
        }
        // update min-dists; track (lmax, slot) in-register
        float lmax = -1.0f;
        int   li   = 0;
#pragma unroll
        for (int i = 0; i < PPT; i++) {
            float dx = __fsub_rn(px[i], cx);
            float dy = __fsub_rn(py[i], cy);
            float dz = __fsub_rn(pz[i], cz);
            float d  = __fadd_rn(__fadd_rn(__fmul_rn(dx, dx), __fmul_rn(dy, dy)),
                                 __fmul_rn(dz, dz));
            float dd = fminf(dist[i], d);
            dist[i] = dd;
            bool gt = dd > lmax;                       // strict: first (smallest i) wins
            lmax = gt ? dd : lmax;
            li   = gt ? i  : li;
        }
        int p = t + (li << 9);
        unsigned long long key =
            ((unsigned long long)__float_as_uint(lmax) << 32) | (unsigned)(~p);
        key = wave_max_u64(key);                       // DPP, valid in lane 63
        if (lane == 63) skey[it & 1][wid] = key;
        __syncthreads();
        unsigned long long k = skey[it & 1][0];
#pragma unroll
        for (int j = 1; j < 8; j++) {
            unsigned long long o = skey[it & 1][j];
            k = (o > k) ? o : k;
        }
        int gi = (int)(~(unsigned)k) & (NN - 1);
        float4 c = lxyz[gi];                           // one broadcast ds_read_b128
        cx = c.x; cy = c.y; cz = c.z;
    }
}

// ---------------------------------------------------------------------------
// Ball query: one wave per query. Ordered compaction of first 32 in-radius
// indices (== reference's where->sort->truncate), pad with first index.
// ---------------------------------------------------------------------------
__global__ __launch_bounds__(256) void ballq_kernel(const float* __restrict__ xyz,
                                                    const float* __restrict__ new_xyz,
                                                    int* __restrict__ idx_out) {
    int q    = blockIdx.x * 4 + (threadIdx.x >> 6);
    int lane = threadIdx.x & 63;
    int b    = q >> 11;                        // q / SS
    const float* x = xyz + b * NN * 3;
    const float* c = new_xyz + q * 3;
    float cx = c[0], cy = c[1], cz = c[2];
    int* out = idx_out + q * KK;
    const float R2 = (float)(0.2 * 0.2);       // match reference double->f32 cast

    int count = 0;
    int first = -1;
    for (int base = 0; base < NN; base += 64) {
        int p = base + lane;
        float dx = __fsub_rn(x[p * 3 + 0], cx);
        float dy = __fsub_rn(x[p * 3 + 1], cy);
        float dz = __fsub_rn(x[p * 3 + 2], cz);
        float d  = __fadd_rn(__fadd_rn(__fmul_rn(dx, dx), __fmul_rn(dy, dy)),
                             __fmul_rn(dz, dz));
        bool in = !(d > R2);
        unsigned long long m = __ballot(in);
        if (first < 0 && m != 0ull) first = base + __ffsll((unsigned long long)m) - 1;
        int pre = __popcll(m & ((1ull << lane) - 1ull));
        int pos = count + pre;
        if (in && pos < KK) out[pos] = p;
        count += __popcll(m);
        if (count >= KK) break;                 // wave-uniform
    }
    for (int i2 = count + lane; i2 < KK; i2 += 64) out[i2] = first;
}

// ---------------------------------------------------------------------------
// MLP helpers (thread-per-point recompute chain; weights via uniform s_loads)
// ---------------------------------------------------------------------------
__device__ __forceinline__ void load_in6(const float* __restrict__ xyz,
                                         const float* __restrict__ points,
                                         const float* __restrict__ new_xyz,
                                         const int* __restrict__ idx, int p, float inx[6]) {
    int bs = p >> 5;
    int b  = bs >> 11;
    int pt = idx[p];
    const float* xb = xyz + ((long)b * NN + pt) * 3;
    const float* pb = points + ((long)b * NN + pt) * 3;
    const float* nx = new_xyz + bs * 3;
    inx[0] = xb[0] - nx[0];
    inx[1] = xb[1] - nx[1];
    inx[2] = xb[2] - nx[2];
    inx[3] = pb[0];
    inx[4] = pb[1];
    inx[5] = pb[2];
}

template <int CIN, int COUT>
__device__ __forceinline__ void linear(const float* __restrict__ w,
                                       const float* __restrict__ bias,
                                       const float* xin, float* yout) {
#pragma unroll
    for (int o = 0; o < COUT; o++) {
        float acc = bias[o];
#pragma unroll
        for (int j = 0; j < CIN; j++) acc = fmaf(w[o * CIN + j], xin[j], acc);
        yout[o] = acc;
    }
}

// compute per-channel BN scale/shift from raw sums (threads 0..C-1)
template <int C>
__device__ __forceinline__ void bn_coef(const float* __restrict__ stats,
                                        const float* __restrict__ g,
                                        const float* __restrict__ be,
                                        float* s_sc, float* s_sh) {
    int t = threadIdx.x;
    if (t < C) {
        float mean = stats[t] * (1.0f / (float)NP);
        float var  = stats[C + t] * (1.0f / (float)NP) - mean * mean;
        float rstd = 1.0f / sqrtf(var + EPSF);
        float sc = g[t] * rstd;
        s_sc[t] = sc;
        s_sh[t] = be[t] - mean * sc;
    }
    __syncthreads();
}

// block-level channel sums via LDS transpose (33.8KB), one atomic/chan/block
template <int C>
__device__ __forceinline__ void accum_stats(const float* y, float* __restrict__ gstats) {
    __shared__ float buf[256][33];
    int t = threadIdx.x;
#pragma unroll
    for (int h = 0; h < C / 32; h++) {
        __syncthreads();
#pragma unroll
        for (int c = 0; c < 32; c++) buf[t][c] = y[h * 32 + c];
        __syncthreads();
        if (t < 32) {
            float s = 0.f, sq = 0.f;
            for (int r = 0; r < 256; r++) {
                float v = buf[r][t];
                s += v;
                sq = fmaf(v, v, sq);
            }
            atomicAdd(&gstats[h * 32 + t], s);
            atomicAdd(&gstats[C + h * 32 + t], sq);
        }
    }
}

__global__ __launch_bounds__(256) void l0_stats_kernel(
    const float* __restrict__ xyz, const float* __restrict__ points,
    const float* __restrict__ new_xyz, const int* __restrict__ idx,
    const float* __restrict__ w0, const float* __restrict__ b0_,
    float* __restrict__ stats0) {
    int p = blockIdx.x * 256 + threadIdx.x;
    float inx[6];
    load_in6(xyz, points, new_xyz, idx, p, inx);
    float y0[32];
    linear<6, 32>(w0, b0_, inx, y0);
    accum_stats<32>(y0, stats0);
}

__global__ __launch_bounds__(256) void l1_stats_kernel(
    const float* __restrict__ xyz, const float* __restrict__ points,
    const float* __restrict__ new_xyz, const int* __restrict__ idx,
    const float* __restrict__ w0, const float* __restrict__ b0_,
    const float* __restrict__ g0, const float* __restrict__ be0,
    const float* __restrict__ w1, const float* __restrict__ b1_,
    const float* __restrict__ stats0, float* __restrict__ stats1) {
    __shared__ float sc0[32], sh0[32];
    bn_coef<32>(stats0, g0, be0, sc0, sh0);
    int p = blockIdx.x * 256 + threadIdx.x;
    float inx[6];
    load_in6(xyz, points, new_xyz, idx, p, inx);
    float y0[32];
    linear<6, 32>(w0, b0_, inx, y0);
#pragma unroll
    for (int c = 0; c < 32; c++) y0[c] = fmaxf(fmaf(y0[c], sc0[c], sh0[c]), 0.f);
    float y1[32];
    linear<32, 32>(w1, b1_, y0, y1);
    accum_stats<32>(y1, stats1);
}

__global__ __launch_bounds__(256) void l2_stats_kernel(
    const float* __restrict__ xyz, const float* __restrict__ points,
    const float* __restrict__ new_xyz, const int* __restrict__ idx,
    const float* __restrict__ w0, const float* __restrict__ b0_,
    const float* __restrict__ g0, const float* __restrict__ be0,
    const float* __restrict__ w1, const float* __restrict__ b1_,
    const float* __restrict__ g1, const float* __restrict__ be1,
    const float* __restrict__ w2, const float* __restrict__ b2_,
    const float* __restrict__ stats0, const float* __restrict__ stats1,
    float* __restrict__ stats2) {
    __shared__ float sc0[32], sh0[32], sc1[32], sh1[32];
    bn_coef<32>(stats0, g0, be0, sc0, sh0);
    bn_coef<32>(stats1, g1, be1, sc1, sh1);
    int p = blockIdx.x * 256 + threadIdx.x;
    float inx[6];
    load_in6(xyz, points, new_xyz, idx, p, inx);
    float y0[32];
    linear<6, 32>(w0, b0_, inx, y0);
#pragma unroll
    for (int c = 0; c < 32; c++) y0[c] = fmaxf(fmaf(y0[c], sc0[c], sh0[c]), 0.f);
    float y1[32];
    linear<32, 32>(w1, b1_, y0, y1);
#pragma unroll
    for (int c = 0; c < 32; c++) y1[c] = fmaxf(fmaf(y1[c], sc1[c], sh1[c]), 0.f);
    float y2[64];
    linear<32, 64>(w2, b2_, y1, y2);
    accum_stats<64>(y2, stats2);
}

__global__ __launch_bounds__(256) void final_kernel(
    const float* __restrict__ xyz, const float* __restrict__ points,
    const float* __restrict__ new_xyz, const int* __restrict__ idx,
    const float* __restrict__ w0, const float* __restrict__ b0_,
    const float* __restrict__ g0, const float* __restrict__ be0,
    const float* __restrict__ w1, const float* __restrict__ b1_,
    const float* __restrict__ g1, const float* __restrict__ be1,
    const float* __restrict__ w2, const float* __restrict__ b2_,
    const float* __restrict__ g2, const float* __restrict__ be2,
    const float* __restrict__ stats0, const float* __restrict__ stats1,
    const float* __restrict__ stats2, float* __restrict__ out_points) {
    __shared__ float sc0[32], sh0[32], sc1[32], sh1[32], sc2[64], sh2[64];
    bn_coef<32>(stats0, g0, be0, sc0, sh0);
    bn_coef<32>(stats1, g1, be1, sc1, sh1);
    bn_coef<64>(stats2, g2, be2, sc2, sh2);
    int p = blockIdx.x * 256 + threadIdx.x;
    float inx[6];
    load_in6(xyz, points, new_xyz, idx, p, inx);
    float y0[32];
    linear<6, 32>(w0, b0_, inx, y0);
#pragma unroll
    for (int c = 0; c < 32; c++) y0[c] = fmaxf(fmaf(y0[c], sc0[c], sh0[c]), 0.f);
    float y1[32];
    linear<32, 32>(w1, b1_, y0, y1);
#pragma unroll
    for (int c = 0; c < 32; c++) y1[c] = fmaxf(fmaf(y1[c], sc1[c], sh1[c]), 0.f);
    float y2[64];
    linear<32, 64>(w2, b2_, y1, y2);
    // BN + relu + max over k (k == lane&31; butterfly within each 32-lane half)
#pragma unroll
    for (int c = 0; c < 64; c++) {
        float v = fmaxf(fmaf(y2[c], sc2[c], sh2[c]), 0.f);
#pragma unroll
        for (int off = 1; off < 32; off <<= 1)
            v = fmaxf(v, __shfl_xor(v, off));
        y2[c] = v;
    }
    int lane = threadIdx.x & 63;
    if ((lane & 31) == 0) {                     // k == 0 lanes write their (b,s) row
        int bs = p >> 5;
        float4* o = (float4*)(out_points + (long)bs * 64);
#pragma unroll
        for (int c4 = 0; c4 < 16; c4++)
            o[c4] = make_float4(y2[c4 * 4], y2[c4 * 4 + 1], y2[c4 * 4 + 2], y2[c4 * 4 + 3]);
    }
}

// ---------------------------------------------------------------------------
extern "C" void kernel_launch(void* const* d_in, const int* in_sizes, int n_in,
                              void* d_out, int out_size, void* d_ws, size_t ws_size,
                              hipStream_t stream) {
    (void)in_sizes; (void)n_in; (void)out_size; (void)ws_size;
    const float* xyz    = (const float*)d_in[0];
    const float* points = (const float*)d_in[1];
    const float* w0  = (const float*)d_in[2];
    const float* b0_ = (const float*)d_in[3];
    const float* g0  = (const float*)d_in[4];
    const float* be0 = (const float*)d_in[5];
    const float* w1  = (const float*)d_in[6];
    const float* b1_ = (const float*)d_in[7];
    const float* g1  = (const float*)d_in[8];
    const float* be1 = (const float*)d_in[9];
    const float* w2  = (const float*)d_in[10];
    const float* b2_ = (const float*)d_in[11];
    const float* g2  = (const float*)d_in[12];
    const float* be2 = (const float*)d_in[13];

    float* out        = (float*)d_out;
    float* out_newxyz = out;                 // (8,2048,3)
    float* out_points = out + BB * SS * 3;   // (8,2048,64)

    int*   idx    = (int*)d_ws;              // NP ints = 2MB
    float* stats  = (float*)d_ws + NP;
    float* stats0 = stats;                   // 64 floats (sum32+sq32)
    float* stats1 = stats + 64;              // 64 floats
    float* stats2 = stats + 128;             // 128 floats (sum64+sq64)

    hipMemsetAsync(stats, 0, 256 * sizeof(float), stream);

    fps_kernel<<<BB, 512, 0, stream>>>(xyz, out_newxyz);
    ballq_kernel<<<BB * SS / 4, 256, 0, stream>>>(xyz, out_newxyz, idx);
    l0_stats_kernel<<<NP / 256, 256, 0, stream>>>(xyz, points, out_newxyz, idx, w0, b0_, stats0);
    l1_stats_kernel<<<NP / 256, 256, 0, stream>>>(xyz, points, out_newxyz, idx,
                                                  w0, b0_, g0, be0, w1, b1_, stats0, stats1);
    l2_stats_kernel<<<NP / 256, 256, 0, stream>>>(xyz, points, out_newxyz, idx,
                                                  w0, b0_, g0, be0, w1, b1_, g1, be1,
                                                  w2, b2_, stats0, stats1, stats2);
    final_kernel<<<NP / 256, 256, 0, stream>>>(xyz, points, out_newxyz, idx,
                                               w0, b0_, g0, be0, w1, b1_, g1, be1,
                                               w2, b2_, g2, be2, stats0, stats1, stats2,
                                               out_points);
}

// Round 4
// 2346.073 us; speedup vs baseline: 1.3114x; 1.0184x over previous
//
#include <hip/hip_runtime.h>
#include <math.h>

#define BB 8
#define NN 8192
#define SS 2048
#define KK 32
#define NP (BB*SS*KK)   /* 524288 points through the MLP */
#define EPSF 1e-5f

typedef float v2f __attribute__((ext_vector_type(2)));

// ---------------------------------------------------------------------------
// DPP-based wave64 max of a u64 key (dist_bits<<32 | ~p). Pure VALU:
// row_shr 1/2/4/8 then row_bcast:15, row_bcast:31 -> lane 63 holds wave max.
// ---------------------------------------------------------------------------
template <int CTRL>
__device__ __forceinline__ unsigned long long dpp_max_step(unsigned long long key) {
    unsigned lo = (unsigned)key, hi = (unsigned)(key >> 32);
    unsigned nlo = (unsigned)__builtin_amdgcn_update_dpp((int)lo, (int)lo, CTRL, 0xf, 0xf, false);
    unsigned nhi = (unsigned)__builtin_amdgcn_update_dpp((int)hi, (int)hi, CTRL, 0xf, 0xf, false);
    unsigned long long nk = ((unsigned long long)nhi << 32) | nlo;
    return nk > key ? nk : key;
}

__device__ __forceinline__ unsigned long long wave_max_u64(unsigned long long key) {
    key = dpp_max_step<0x111>(key);  // row_shr:1
    key = dpp_max_step<0x112>(key);  // row_shr:2
    key = dpp_max_step<0x114>(key);  // row_shr:4
    key = dpp_max_step<0x118>(key);  // row_shr:8
    key = dpp_max_step<0x142>(key);  // row_bcast:15
    key = dpp_max_step<0x143>(key);  // row_bcast:31
    return key;                      // valid in lane 63
}

// ---------------------------------------------------------------------------
// FPS: one block per batch, 512 threads, ONE barrier per iteration.
// VALU-issue-bound (83% VALU busy on active CUs at R2) -> packed-fp32
// (v_pk_add/mul_f32) dist update: 2 points per instruction for the
// sub/square/sum chain. fp contract(off) keeps each half's rounding
// identical to the scalar reference chain ((dx*dx+dy*dy)+dz*dz).
// Argmax tracking, DPP u64 wave max, parity LDS slots unchanged (R2).
// ---------------------------------------------------------------------------
__global__ __launch_bounds__(512) void fps_kernel(const float* __restrict__ xyz,
                                                  float* __restrict__ out_newxyz) {
#pragma clang fp contract(off)
    const int T = 512;
    const int NPAIR = 8;             // 16 points per thread = 8 packed pairs
    int b = blockIdx.x;
    int t = threadIdx.x;
    int wid  = t >> 6;
    int lane = t & 63;
    const float* x = xyz + b * NN * 3;
    float* nout = out_newxyz + b * SS * 3;

    __shared__ float4 lxyz[NN];                       // 128 KB coord copy
    __shared__ unsigned long long skey[2][8];         // parity-buffered wave keys

    v2f px2[NPAIR], py2[NPAIR], pz2[NPAIR], d2[NPAIR];
#pragma unroll
    for (int j = 0; j < NPAIR; j++) {
        int p0 = t + (2 * j) * T;                     // slot 2j
        int p1 = p0 + T;                              // slot 2j+1
        float ax = x[p0 * 3 + 0], ay = x[p0 * 3 + 1], az = x[p0 * 3 + 2];
        float bx = x[p1 * 3 + 0], by = x[p1 * 3 + 1], bz = x[p1 * 3 + 2];
        px2[j].x = ax; px2[j].y = bx;
        py2[j].x = ay; py2[j].y = by;
        pz2[j].x = az; pz2[j].y = bz;
        lxyz[p0] = make_float4(ax, ay, az, 0.f);
        lxyz[p1] = make_float4(bx, by, bz, 0.f);
        d2[j].x = 1e10f; d2[j].y = 1e10f;
    }
    __syncthreads();
    float4 c0 = lxyz[0];                              // far = 0 initially
    float cx = c0.x, cy = c0.y, cz = c0.z;

    for (int it = 0; it < SS; it++) {
        if (t == 0) {                                  // record current far point
            nout[it * 3 + 0] = cx;
            nout[it * 3 + 1] = cy;
            nout[it * 3 + 2] = cz;
        }
        v2f cxx, cyy, czz;
        cxx.x = cx; cxx.y = cx;
        cyy.x = cy; cyy.y = cy;
        czz.x = cz; czz.y = cz;
        // packed update of min-dists; scalar (lmax, slot) tracking in scan
        // order 0..15 with strict > (first/smallest-index max wins == np.argmax)
        float lmax = -1.0f;
        int   li   = 0;
#pragma unroll
        for (int j = 0; j < NPAIR; j++) {
            v2f dx = px2[j] - cxx;                     // v_pk_add_f32 (neg)
            v2f dy = py2[j] - cyy;
            v2f dz = pz2[j] - czz;
            v2f sx = dx * dx;                          // v_pk_mul_f32
            v2f sy = dy * dy;
            v2f sz = dz * dz;
            v2f ss = (sx + sy) + sz;                   // 2x v_pk_add_f32
            float e0 = fminf(d2[j].x, ss.x);
            float e1 = fminf(d2[j].y, ss.y);
            d2[j].x = e0;
            d2[j].y = e1;
            bool g0 = e0 > lmax;
            lmax = g0 ? e0 : lmax;
            li   = g0 ? (2 * j) : li;
            bool g1 = e1 > lmax;
            lmax = g1 ? e1 : lmax;
            li   = g1 ? (2 * j + 1) : li;
        }
        int p = t + (li << 9);
        unsigned long long key =
            ((unsigned long long)__float_as_uint(lmax) << 32) | (unsigned)(~p);
        key = wave_max_u64(key);                       // DPP, valid in lane 63
        if (lane == 63) skey[it & 1][wid] = key;
        __syncthreads();
        unsigned long long k = skey[it & 1][0];
#pragma unroll
        for (int j = 1; j < 8; j++) {
            unsigned long long o = skey[it & 1][j];
            k = (o > k) ? o : k;
        }
        int gi = (int)(~(unsigned)k) & (NN - 1);
        float4 c = lxyz[gi];                           // one broadcast ds_read_b128
        cx = c.x; cy = c.y; cz = c.z;
    }
}

// ---------------------------------------------------------------------------
// Ball query: one wave per query. Ordered compaction of first 32 in-radius
// indices (== reference's where->sort->truncate), pad with first index.
// ---------------------------------------------------------------------------
__global__ __launch_bounds__(256) void ballq_kernel(const float* __restrict__ xyz,
                                                    const float* __restrict__ new_xyz,
                                                    int* __restrict__ idx_out) {
    int q    = blockIdx.x * 4 + (threadIdx.x >> 6);
    int lane = threadIdx.x & 63;
    int b    = q >> 11;                        // q / SS
    const float* x = xyz + b * NN * 3;
    const float* c = new_xyz + q * 3;
    float cx = c[0], cy = c[1], cz = c[2];
    int* out = idx_out + q * KK;
    const float R2 = (float)(0.2 * 0.2);       // match reference double->f32 cast

    int count = 0;
    int first = -1;
    for (int base = 0; base < NN; base += 64) {
        int p = base + lane;
        float dx = __fsub_rn(x[p * 3 + 0], cx);
        float dy = __fsub_rn(x[p * 3 + 1], cy);
        float dz = __fsub_rn(x[p * 3 + 2], cz);
        float d  = __fadd_rn(__fadd_rn(__fmul_rn(dx, dx), __fmul_rn(dy, dy)),
                             __fmul_rn(dz, dz));
        bool in = !(d > R2);
        unsigned long long m = __ballot(in);
        if (first < 0 && m != 0ull) first = base + __ffsll((unsigned long long)m) - 1;
        int pre = __popcll(m & ((1ull << lane) - 1ull));
        int pos = count + pre;
        if (in && pos < KK) out[pos] = p;
        count += __popcll(m);
        if (count >= KK) break;                 // wave-uniform
    }
    for (int i2 = count + lane; i2 < KK; i2 += 64) out[i2] = first;
}

// ---------------------------------------------------------------------------
// MLP helpers (thread-per-point recompute chain; weights via uniform s_loads)
// ---------------------------------------------------------------------------
__device__ __forceinline__ void load_in6(const float* __restrict__ xyz,
                                         const float* __restrict__ points,
                                         const float* __restrict__ new_xyz,
                                         const int* __restrict__ idx, int p, float inx[6]) {
    int bs = p >> 5;
    int b  = bs >> 11;
    int pt = idx[p];
    const float* xb = xyz + ((long)b * NN + pt) * 3;
    const float* pb = points + ((long)b * NN + pt) * 3;
    const float* nx = new_xyz + bs * 3;
    inx[0] = xb[0] - nx[0];
    inx[1] = xb[1] - nx[1];
    inx[2] = xb[2] - nx[2];
    inx[3] = pb[0];
    inx[4] = pb[1];
    inx[5] = pb[2];
}

template <int CIN, int COUT>
__device__ __forceinline__ void linear(const float* __restrict__ w,
                                       const float* __restrict__ bias,
                                       const float* xin, float* yout) {
#pragma unroll
    for (int o = 0; o < COUT; o++) {
        float acc = bias[o];
#pragma unroll
        for (int j = 0; j < CIN; j++) acc = fmaf(w[o * CIN + j], xin[j], acc);
        yout[o] = acc;
    }
}

// compute per-channel BN scale/shift from raw sums (threads 0..C-1)
template <int C>
__device__ __forceinline__ void bn_coef(const float* __restrict__ stats,
                                        const float* __restrict__ g,
                                        const float* __restrict__ be,
                                        float* s_sc, float* s_sh) {
    int t = threadIdx.x;
    if (t < C) {
        float mean = stats[t] * (1.0f / (float)NP);
        float var  = stats[C + t] * (1.0f / (float)NP) - mean * mean;
        float rstd = 1.0f / sqrtf(var + EPSF);
        float sc = g[t] * rstd;
        s_sc[t] = sc;
        s_sh[t] = be[t] - mean * sc;
    }
    __syncthreads();
}

// block-level channel sums via LDS transpose (33.8KB), one atomic/chan/block
template <int C>
__device__ __forceinline__ void accum_stats(const float* y, float* __restrict__ gstats) {
    __shared__ float buf[256][33];
    int t = threadIdx.x;
#pragma unroll
    for (int h = 0; h < C / 32; h++) {
        __syncthreads();
#pragma unroll
        for (int c = 0; c < 32; c++) buf[t][c] = y[h * 32 + c];
        __syncthreads();
        if (t < 32) {
            float s = 0.f, sq = 0.f;
            for (int r = 0; r < 256; r++) {
                float v = buf[r][t];
                s += v;
                sq = fmaf(v, v, sq);
            }
            atomicAdd(&gstats[h * 32 + t], s);
            atomicAdd(&gstats[C + h * 32 + t], sq);
        }
    }
}

__global__ __launch_bounds__(256) void l0_stats_kernel(
    const float* __restrict__ xyz, const float* __restrict__ points,
    const float* __restrict__ new_xyz, const int* __restrict__ idx,
    const float* __restrict__ w0, const float* __restrict__ b0_,
    float* __restrict__ stats0) {
    int p = blockIdx.x * 256 + threadIdx.x;
    float inx[6];
    load_in6(xyz, points, new_xyz, idx, p, inx);
    float y0[32];
    linear<6, 32>(w0, b0_, inx, y0);
    accum_stats<32>(y0, stats0);
}

__global__ __launch_bounds__(256) void l1_stats_kernel(
    const float* __restrict__ xyz, const float* __restrict__ points,
    const float* __restrict__ new_xyz, const int* __restrict__ idx,
    const float* __restrict__ w0, const float* __restrict__ b0_,
    const float* __restrict__ g0, const float* __restrict__ be0,
    const float* __restrict__ w1, const float* __restrict__ b1_,
    const float* __restrict__ stats0, float* __restrict__ stats1) {
    __shared__ float sc0[32], sh0[32];
    bn_coef<32>(stats0, g0, be0, sc0, sh0);
    int p = blockIdx.x * 256 + threadIdx.x;
    float inx[6];
    load_in6(xyz, points, new_xyz, idx, p, inx);
    float y0[32];
    linear<6, 32>(w0, b0_, inx, y0);
#pragma unroll
    for (int c = 0; c < 32; c++) y0[c] = fmaxf(fmaf(y0[c], sc0[c], sh0[c]), 0.f);
    float y1[32];
    linear<32, 32>(w1, b1_, y0, y1);
    accum_stats<32>(y1, stats1);
}

__global__ __launch_bounds__(256) void l2_stats_kernel(
    const float* __restrict__ xyz, const float* __restrict__ points,
    const float* __restrict__ new_xyz, const int* __restrict__ idx,
    const float* __restrict__ w0, const float* __restrict__ b0_,
    const float* __restrict__ g0, const float* __restrict__ be0,
    const float* __restrict__ w1, const float* __restrict__ b1_,
    const float* __restrict__ g1, const float* __restrict__ be1,
    const float* __restrict__ w2, const float* __restrict__ b2_,
    const float* __restrict__ stats0, const float* __restrict__ stats1,
    float* __restrict__ stats2) {
    __shared__ float sc0[32], sh0[32], sc1[32], sh1[32];
    bn_coef<32>(stats0, g0, be0, sc0, sh0);
    bn_coef<32>(stats1, g1, be1, sc1, sh1);
    int p = blockIdx.x * 256 + threadIdx.x;
    float inx[6];
    load_in6(xyz, points, new_xyz, idx, p, inx);
    float y0[32];
    linear<6, 32>(w0, b0_, inx, y0);
#pragma unroll
    for (int c = 0; c < 32; c++) y0[c] = fmaxf(fmaf(y0[c], sc0[c], sh0[c]), 0.f);
    float y1[32];
    linear<32, 32>(w1, b1_, y0, y1);
#pragma unroll
    for (int c = 0; c < 32; c++) y1[c] = fmaxf(fmaf(y1[c], sc1[c], sh1[c]), 0.f);
    float y2[64];
    linear<32, 64>(w2, b2_, y1, y2);
    accum_stats<64>(y2, stats2);
}

__global__ __launch_bounds__(256) void final_kernel(
    const float* __restrict__ xyz, const float* __restrict__ points,
    const float* __restrict__ new_xyz, const int* __restrict__ idx,
    const float* __restrict__ w0, const float* __restrict__ b0_,
    const float* __restrict__ g0, const float* __restrict__ be0,
    const float* __restrict__ w1, const float* __restrict__ b1_,
    const float* __restrict__ g1, const float* __restrict__ be1,
    const float* __restrict__ w2, const float* __restrict__ b2_,
    const float* __restrict__ g2, const float* __restrict__ be2,
    const float* __restrict__ stats0, const float* __restrict__ stats1,
    const float* __restrict__ stats2, float* __restrict__ out_points) {
    __shared__ float sc0[32], sh0[32], sc1[32], sh1[32], sc2[64], sh2[64];
    bn_coef<32>(stats0, g0, be0, sc0, sh0);
    bn_coef<32>(stats1, g1, be1, sc1, sh1);
    bn_coef<64>(stats2, g2, be2, sc2, sh2);
    int p = blockIdx.x * 256 + threadIdx.x;
    float inx[6];
    load_in6(xyz, points, new_xyz, idx, p, inx);
    float y0[32];
    linear<6, 32>(w0, b0_, inx, y0);
#pragma unroll
    for (int c = 0; c < 32; c++) y0[c] = fmaxf(fmaf(y0[c], sc0[c], sh0[c]), 0.f);
    float y1[32];
    linear<32, 32>(w1, b1_, y0, y1);
#pragma unroll
    for (int c = 0; c < 32; c++) y1[c] = fmaxf(fmaf(y1[c], sc1[c], sh1[c]), 0.f);
    float y2[64];
    linear<32, 64>(w2, b2_, y1, y2);
    // BN + relu + max over k (k == lane&31; butterfly within each 32-lane half)
#pragma unroll
    for (int c = 0; c < 64; c++) {
        float v = fmaxf(fmaf(y2[c], sc2[c], sh2[c]), 0.f);
#pragma unroll
        for (int off = 1; off < 32; off <<= 1)
            v = fmaxf(v, __shfl_xor(v, off));
        y2[c] = v;
    }
    int lane = threadIdx.x & 63;
    if ((lane & 31) == 0) {                     // k == 0 lanes write their (b,s) row
        int bs = p >> 5;
        float4* o = (float4*)(out_points + (long)bs * 64);
#pragma unroll
        for (int c4 = 0; c4 < 16; c4++)
            o[c4] = make_float4(y2[c4 * 4], y2[c4 * 4 + 1], y2[c4 * 4 + 2], y2[c4 * 4 + 3]);
    }
}

// ---------------------------------------------------------------------------
extern "C" void kernel_launch(void* const* d_in, const int* in_sizes, int n_in,
                              void* d_out, int out_size, void* d_ws, size_t ws_size,
                              hipStream_t stream) {
    (void)in_sizes; (void)n_in; (void)out_size; (void)ws_size;
    const float* xyz    = (const float*)d_in[0];
    const float* points = (const float*)d_in[1];
    const float* w0  = (const float*)d_in[2];
    const float* b0_ = (const float*)d_in[3];
    const float* g0  = (const float*)d_in[4];
    const float* be0 = (const float*)d_in[5];
    const float* w1  = (const float*)d_in[6];
    const float* b1_ = (const float*)d_in[7];
    const float* g1  = (const float*)d_in[8];
    const float* be1 = (const float*)d_in[9];
    const float* w2  = (const float*)d_in[10];
    const float* b2_ = (const float*)d_in[11];
    const float* g2  = (const float*)d_in[12];
    const float* be2 = (const float*)d_in[13];

    float* out        = (float*)d_out;
    float* out_newxyz = out;                 // (8,2048,3)
    float* out_points = out + BB * SS * 3;   // (8,2048,64)

    int*   idx    = (int*)d_ws;              // NP ints = 2MB
    float* stats  = (float*)d_ws + NP;
    float* stats0 = stats;                   // 64 floats (sum32+sq32)
    float* stats1 = stats + 64;              // 64 floats
    float* stats2 = stats + 128;             // 128 floats (sum64+sq64)

    hipMemsetAsync(stats, 0, 256 * sizeof(float), stream);

    fps_kernel<<<BB, 512, 0, stream>>>(xyz, out_newxyz);
    ballq_kernel<<<BB * SS / 4, 256, 0, stream>>>(xyz, out_newxyz, idx);
    l0_stats_kernel<<<NP / 256, 256, 0, stream>>>(xyz, points, out_newxyz, idx, w0, b0_, stats0);
    l1_stats_kernel<<<NP / 256, 256, 0, stream>>>(xyz, points, out_newxyz, idx,
                                                  w0, b0_, g0, be0, w1, b1_, stats0, stats1);
    l2_stats_kernel<<<NP / 256, 256, 0, stream>>>(xyz, points, out_newxyz, idx,
                                                  w0, b0_, g0, be0, w1, b1_, g1, be1,
                                                  w2, b2_, stats0, stats1, stats2);
    final_kernel<<<NP / 256, 256, 0, stream>>>(xyz, points, out_newxyz, idx,
                                               w0, b0_, g0, be0, w1, b1_, g1, be1,
                                               w2, b2_, g2, be2, stats0, stats1, stats2,
                                               out_points);
}